// Round 12
// baseline (25603.448 us; speedup 1.0000x reference)
//
#include <hip/hip_runtime.h>
#include <math.h>

#define H 1024
#define D 256
#define NB 256
#define NT 512
#define LW 64   // warmup (teacher-forced) length

typedef float f32x4 __attribute__((ext_vector_type(4)));

__device__ __forceinline__ float sigf(float v) { return 1.f / (1.f + __expf(-v)); }

__device__ __forceinline__ float waveReduce(float v) {
#pragma unroll
    for (int off = 32; off > 0; off >>= 1) v += __shfl_xor(v, off, 64);
    return v;
}

// LLC-coherent ops (sc0 sc1 bypass L1/L2) — no cache-maintenance fences needed.
__device__ __forceinline__ f32x4 ldg4_nw(const float* p) {   // issue only
    f32x4 r;
    asm volatile("global_load_dwordx4 %0, %1, off sc0 sc1" : "=v"(r) : "v"(p) : "memory");
    return r;
}
// wait with loaded value data-chained through (rule-18 safe)
__device__ __forceinline__ void vm_wait1(f32x4& a) {
    asm volatile("s_waitcnt vmcnt(0)" : "+v"(a) :: "memory");
    __builtin_amdgcn_sched_barrier(0);
}
__device__ __forceinline__ void stg4_sc(float* p, f32x4 v) {
    asm volatile("global_store_dwordx4 %0, %1, off sc0 sc1" :: "v"(p), "v"(v) : "memory");
}
__device__ __forceinline__ void stg1_sc(float* p, float v) {
    asm volatile("global_store_dword %0, %1, off sc0 sc1" :: "v"(p), "v"(v) : "memory");
}

// Tags: |value| < 1 always; producer stores value + tag, tag = 8*(s&3)-12 in
// {-12,-4,4,12}. Valid iff |x - tag| < 2. Zero / 0xAA / stale / torn chunks
// can never false-validate (region spacing 8 >> threshold 2 + |v|<1).
__device__ __forceinline__ float tagf(int i) { return 8.0f * (float)(i & 3) - 12.0f; }
__device__ __forceinline__ bool vld4(f32x4 c, float tg) {
    float m = fmaxf(fmaxf(fabsf(c.x - tg), fabsf(c.y - tg)),
                    fmaxf(fabsf(c.z - tg), fabsf(c.w - tg)));
    return m < 2.0f;
}

// ---- static exchange buffers (packed) ----
// [0 .. 256)          inp entries (1 float per block)
// [256 + (l*2+p)*H)   hg[layer l][ping-pong p], 4 floats per block, packed
#define EXN (256 + 6 * H)
__device__ float g_ex[EXN];

__global__ void ws_clear() {
    int i = blockIdx.x * blockDim.x + threadIdx.x;
    for (; i < EXN; i += gridDim.x * blockDim.x) g_ex[i] = 0.f;
}

__global__ __launch_bounds__(NT, 2) void rnn_reg9(
    const float* __restrict__ x, const float* __restrict__ h0in, const float* __restrict__ c0,
    const float* __restrict__ Wih0, const float* __restrict__ Whh0,
    const float* __restrict__ Wih1, const float* __restrict__ Whh1,
    const float* __restrict__ Wih2, const float* __restrict__ Whh2,
    const float* __restrict__ b_ih, const float* __restrict__ b_hh,
    const float* __restrict__ Wfc, const float* __restrict__ bfc,
    float* __restrict__ out, int T, int L)
{
    const int b = blockIdx.x;
    const int tid = threadIdx.x;
    const int w = tid >> 6;
    const int lane = tid & 63;
    const int gate = w & 3;          // i,f,g,o
    const int up = w >> 2;           // 0..1 -> unit pair
    const int u0 = b * 4 + 2 * up;
    const int r0 = gate * H + u0;
    const int r1 = r0 + 1;
    const int off = lane * 4;

    float* inpw = g_ex;

    __shared__ __align__(16) float lds_h0[2 * H], lds_h1[2 * H], lds_h2[2 * H];
    __shared__ __align__(16) float lds_fc[H];
    __shared__ __align__(16) float lds_inp[D];
    __shared__ float lds_x[LW];
    __shared__ float gate_buf[16];
    __shared__ float red[8];
    __shared__ float c_st[12];

    // ---- one-time: weights -> registers (2 rows/wave, 42 float4) ----
    float4 wA0[5], wB0[5], wA1[8], wB1[8], wA2[8], wB2[8];
    wA0[0] = *(const float4*)(Wih0 + (size_t)r0 * 256 + off);
    wB0[0] = *(const float4*)(Wih0 + (size_t)r1 * 256 + off);
#pragma unroll
    for (int j = 0; j < 4; ++j) {
        wA0[j + 1] = *(const float4*)(Whh0 + (size_t)r0 * H + j * 256 + off);
        wB0[j + 1] = *(const float4*)(Whh0 + (size_t)r1 * H + j * 256 + off);
        wA1[j]     = *(const float4*)(Wih1 + (size_t)r0 * H + j * 256 + off);
        wB1[j]     = *(const float4*)(Wih1 + (size_t)r1 * H + j * 256 + off);
        wA1[j + 4] = *(const float4*)(Whh1 + (size_t)r0 * H + j * 256 + off);
        wB1[j + 4] = *(const float4*)(Whh1 + (size_t)r1 * H + j * 256 + off);
        wA2[j]     = *(const float4*)(Wih2 + (size_t)r0 * H + j * 256 + off);
        wB2[j]     = *(const float4*)(Wih2 + (size_t)r1 * H + j * 256 + off);
        wA2[j + 4] = *(const float4*)(Whh2 + (size_t)r0 * H + j * 256 + off);
        wB2[j + 4] = *(const float4*)(Whh2 + (size_t)r1 * H + j * 256 + off);
    }
    const float bA0 = b_ih[r0] + b_hh[r0];
    const float bB0 = b_ih[r1] + b_hh[r1];
    const float bA1 = b_ih[4 * H + r0] + b_hh[4 * H + r0];
    const float bB1 = b_ih[4 * H + r1] + b_hh[4 * H + r1];
    const float bA2 = b_ih[8 * H + r0] + b_hh[8 * H + r0];
    const float bB2 = b_ih[8 * H + r1] + b_hh[8 * H + r1];
    const float bfc_b = bfc[b];

#define KA(v) asm volatile("" : "+v"(v.x), "+v"(v.y), "+v"(v.z), "+v"(v.w))
#pragma unroll
    for (int j = 0; j < 5; ++j) { KA(wA0[j]); KA(wB0[j]); }
#pragma unroll
    for (int j = 0; j < 8; ++j) { KA(wA1[j]); KA(wB1[j]); KA(wA2[j]); KA(wB2[j]); }
#undef KA

    // ---- prologue: initial states into LDS slot 1 (read by step 0) ----
    for (int i = tid; i < H; i += NT) {
        lds_fc[i]     = Wfc[(size_t)b * H + i];
        lds_h0[H + i] = h0in[i];
        lds_h1[H + i] = h0in[H + i];
        lds_h2[H + i] = h0in[2 * H + i];
    }
    if (tid < LW && tid < L) lds_x[tid] = x[(size_t)b * L + tid];
    if (tid < 12) c_st[tid] = c0[(tid >> 2) * H + b * 4 + (tid & 3)];
    if (tid == 0) {
        float v = x[(size_t)b * L];
        out[(size_t)b * T] = v;                 // out column 0
        lds_inp[b] = v;                         // self mirror
        stg1_sc(inpw + b, v + tagf(0));         // step-0 input
    }
    __syncthreads();

    // h-gather: waves 0..3, ONE chunk per lane per round; self via LDS mirror.
#define POLLH(SRC, DST, TG)                                                    \
    if (w < 4) {                                                               \
        const int c_ = w * 64 + lane;                                          \
        const float* s_ = (SRC) + c_ * 4;                                      \
        float* d_ = (DST) + c_ * 4;                                            \
        const float tg_ = (TG);                                                \
        bool done = (c_ == b);                                                 \
        int spin = 0;                                                          \
        for (;;) {                                                             \
            f32x4 v = {0, 0, 0, 0};                                            \
            if (!done) v = ldg4_nw(s_);                                        \
            vm_wait1(v);                                                       \
            if (!done && vld4(v, tg_)) {                                       \
                f32x4 u = {v.x - tg_, v.y - tg_, v.z - tg_, v.w - tg_};        \
                *(f32x4*)d_ = u;                                               \
                done = true;                                                   \
            }                                                                  \
            if (__all(done)) break;                                            \
            if (++spin > 8) __builtin_amdgcn_s_sleep(4);                       \
            else            __builtin_amdgcn_s_sleep(1);                       \
        }                                                                      \
    }

#define DOT(WA, WB, N1, P1, N2, P2, BA, BB)                                   \
    {                                                                         \
        float4 a0 = {0,0,0,0}, a1 = {0,0,0,0};                                \
        _Pragma("unroll")                                                     \
        for (int j = 0; j < N1; ++j) {                                        \
            float4 v = *(const float4*)((P1) + j * 256 + off);                \
            a0.x += WA[j].x*v.x; a0.y += WA[j].y*v.y;                         \
            a0.z += WA[j].z*v.z; a0.w += WA[j].w*v.w;                         \
            a1.x += WB[j].x*v.x; a1.y += WB[j].y*v.y;                         \
            a1.z += WB[j].z*v.z; a1.w += WB[j].w*v.w;                         \
        }                                                                     \
        _Pragma("unroll")                                                     \
        for (int j = 0; j < N2; ++j) {                                        \
            float4 v = *(const float4*)((P2) + j * 256 + off);                \
            a0.x += WA[N1+j].x*v.x; a0.y += WA[N1+j].y*v.y;                   \
            a0.z += WA[N1+j].z*v.z; a0.w += WA[N1+j].w*v.w;                   \
            a1.x += WB[N1+j].x*v.x; a1.y += WB[N1+j].y*v.y;                   \
            a1.z += WB[N1+j].z*v.z; a1.w += WB[N1+j].w*v.w;                   \
        }                                                                     \
        float s0 = waveReduce(a0.x + a0.y + a0.z + a0.w);                     \
        float s1 = waveReduce(a1.x + a1.y + a1.z + a1.w);                     \
        if (lane == 0) {                                                      \
            gate_buf[(2*up)*4 + gate]   = s0 + BA;                            \
            gate_buf[(2*up+1)*4 + gate] = s1 + BB;                            \
        }                                                                     \
    }

    // wave 7: combine gates; one packed tagged global store + own-LDS mirror.
#define COMBINE(LIDX, HGPTR, TG, MIRROR)                                      \
    if (w == 7) {                                                             \
        float hn = 0.f;                                                       \
        if (lane < 4) {                                                       \
            float gi = gate_buf[lane*4+0], gf = gate_buf[lane*4+1];           \
            float gg = gate_buf[lane*4+2], go = gate_buf[lane*4+3];           \
            float cn = sigf(gf)*c_st[(LIDX)*4+lane] + sigf(gi)*tanhf(gg);     \
            c_st[(LIDX)*4+lane] = cn;                                         \
            hn = sigf(go)*tanhf(cn);                                          \
        }                                                                     \
        float v0=__shfl(hn,0), v1=__shfl(hn,1), v2=__shfl(hn,2), v3=__shfl(hn,3); \
        if (lane == 0) {                                                      \
            f32x4 pk = {v0+(TG), v1+(TG), v2+(TG), v3+(TG)};                  \
            stg4_sc((HGPTR) + b*4, pk);                                       \
            f32x4 raw = {v0, v1, v2, v3};                                     \
            *(f32x4*)((MIRROR) + b*4) = raw;                                  \
        }                                                                     \
    }

    for (int s = 0; s < T - 1; ++s) {
        const int ps = s & 1;
        const float tagS = tagf(s);
        float* hg0 = g_ex + 256 + (0 * 2 + ps) * H;
        float* hg1 = g_ex + 256 + (1 * 2 + ps) * H;
        float* hg2 = g_ex + 256 + (2 * 2 + ps) * H;

        // ---------- phase A: gather inp (wave 0, 4 entries/lane), layer 0 ----------
        if (w == 0) {
            const int e = lane * 4;
            bool d0 = (e == b), d1 = (e + 1 == b), d2 = (e + 2 == b), d3 = (e + 3 == b);
            int spin = 0;
            for (;;) {
                f32x4 v = ldg4_nw(inpw + e);
                vm_wait1(v);
                if (!d0 && fabsf(v.x - tagS) < 2.f) { d0 = true; lds_inp[e]     = v.x - tagS; }
                if (!d1 && fabsf(v.y - tagS) < 2.f) { d1 = true; lds_inp[e + 1] = v.y - tagS; }
                if (!d2 && fabsf(v.z - tagS) < 2.f) { d2 = true; lds_inp[e + 2] = v.z - tagS; }
                if (!d3 && fabsf(v.w - tagS) < 2.f) { d3 = true; lds_inp[e + 3] = v.w - tagS; }
                if (__all(d0 && d1 && d2 && d3)) break;
                if (++spin > 8) __builtin_amdgcn_s_sleep(4);
                else            __builtin_amdgcn_s_sleep(1);
            }
        }
        __syncthreads();
        DOT(wA0, wB0, 1, lds_inp, 4, lds_h0 + (ps ^ 1) * H, bA0, bB0)
        __syncthreads();
        COMBINE(0, hg0, tagS, lds_h0 + ps * H)

        // ---------- phase B: gather h0, layer 1 ----------
        POLLH(hg0, lds_h0 + ps * H, tagS)
        __syncthreads();
        DOT(wA1, wB1, 4, lds_h0 + ps * H, 4, lds_h1 + (ps ^ 1) * H, bA1, bB1)
        __syncthreads();
        COMBINE(1, hg1, tagS, lds_h1 + ps * H)

        // ---------- phase C: gather h1, layer 2 ----------
        POLLH(hg1, lds_h1 + ps * H, tagS)
        __syncthreads();
        DOT(wA2, wB2, 4, lds_h1 + ps * H, 4, lds_h2 + (ps ^ 1) * H, bA2, bB2)
        __syncthreads();
        COMBINE(2, hg2, tagS, lds_h2 + ps * H)

        // ---------- phase D: gather h2 (next-step recurrent) + fc ----------
        POLLH(hg2, lds_h2 + ps * H, tagS)
        __syncthreads();
        if (s + 1 >= L) {
            float2 pv = *(const float2*)(lds_h2 + ps * H + 2 * tid);
            float2 fw = *(const float2*)(lds_fc + 2 * tid);
            float a = waveReduce(pv.x * fw.x + pv.y * fw.y);
            if (lane == 0) red[w] = a;
            __syncthreads();
        }
        if (w == 7 && lane == 0) {
            float nxt;
            if (s + 1 < L) {
                nxt = lds_x[s + 1];
            } else {
                float sfc = red[0] + red[1] + red[2] + red[3]
                          + red[4] + red[5] + red[6] + red[7];
                nxt = sigf(sfc + bfc_b);
            }
            out[(size_t)b * T + s + 1] = nxt;
            lds_inp[b] = nxt;                        // self mirror for next A
            stg1_sc(inpw + b, nxt + tagf(s + 1));
        }
    }
#undef DOT
#undef COMBINE
#undef POLLH
}

extern "C" void kernel_launch(void* const* d_in, const int* in_sizes, int n_in,
                              void* d_out, int out_size, void* d_ws, size_t ws_size,
                              hipStream_t stream) {
    const float* x    = (const float*)d_in[0];
    const float* h0   = (const float*)d_in[1];
    const float* c0   = (const float*)d_in[2];
    const float* Wih0 = (const float*)d_in[3];
    const float* Whh0 = (const float*)d_in[4];
    const float* Wih1 = (const float*)d_in[5];
    const float* Whh1 = (const float*)d_in[6];
    const float* Wih2 = (const float*)d_in[7];
    const float* Whh2 = (const float*)d_in[8];
    const float* bih  = (const float*)d_in[9];
    const float* bhh  = (const float*)d_in[10];
    const float* Wfc  = (const float*)d_in[11];
    const float* bfc  = (const float*)d_in[12];

    float* out = (float*)d_out;

    int T = out_size / D;        // 2048
    int L = in_sizes[0] / D;     // 64

    ws_clear<<<16, 512, 0, stream>>>();

    void* args[] = { &x, &h0, &c0, &Wih0, &Whh0, &Wih1, &Whh1, &Wih2, &Whh2,
                     &bih, &bhh, &Wfc, &bfc, &out, &T, &L };

    (void)hipLaunchCooperativeKernel((void*)rnn_reg9, dim3(NB), dim3(NT), args, 0, stream);
}